// Round 9
// baseline (382.813 us; speedup 1.0000x reference)
//
#include <hip/hip_runtime.h>

#define FDIM   128
#define HEADS  4
#define ALPHA  0.2f

typedef float v2f __attribute__((ext_vector_type(2)));

__device__ __forceinline__ float readlane_f(float v, int lane) {
  return __int_as_float(__builtin_amdgcn_readlane(__float_as_int(v), lane));
}

// ------- per-node scores + bf16-pack of x + per-NODE edge histogram ----------
// Butterfly reduction: 10 shuffles/wave.  Histogram slice: blocks [0,HB) do
// direct global atomics on hist[n] (per-node counting sort granularity).
__global__ __launch_bounds__(256) void score_kernel(
    const float* __restrict__ x, const float* __restrict__ W,
    const float* __restrict__ a, float* __restrict__ s_src,
    float* __restrict__ s_dst, unsigned int* __restrict__ xb,
    const int* __restrict__ src, int* __restrict__ hist,
    int E, int HB, int n) {
  int lane = threadIdx.x & 63;
  int node = (blockIdx.x << 2) + (threadIdx.x >> 6);
  if (node < n) {
    const float2* x2 = (const float2*)x;
    const float2* W2 = (const float2*)W;
    const float2* a2 = (const float2*)a;
    float2 xv = x2[(size_t)node * 64 + lane];

    // bf16 pack (round-to-nearest-even)
    unsigned int u0 = __float_as_uint(xv.x);
    unsigned int u1 = __float_as_uint(xv.y);
    u0 += 0x7fffu + ((u0 >> 16) & 1u);
    u1 += 0x7fffu + ((u1 >> 16) & 1u);
    xb[(size_t)node * 64 + lane] = (u0 >> 16) | (u1 & 0xffff0000u);

    float p[8];   // p[0..3] = rs per head, p[4..7] = rd per head
#pragma unroll
    for (int k = 0; k < HEADS; k++) {
      float2 wv = W2[k * 64 + lane];
      float hx = xv.x * wv.x, hy = xv.y * wv.y;
      float2 as_ = a2[k * 128 + lane];        // a[k, 0:F]
      float2 ad_ = a2[k * 128 + 64 + lane];   // a[k, F:2F]
      p[k]     = hx * as_.x + hy * as_.y;
      p[4 + k] = hx * ad_.x + hy * ad_.y;
    }

    bool h5 = (lane & 32) != 0;
    float q[4];
#pragma unroll
    for (int k = 0; k < 4; k++) {
      float send = h5 ? p[k] : p[4 + k];
      float got = __shfl_xor(send, 32);
      q[k] = (h5 ? p[4 + k] : p[k]) + got;
    }
    bool h4 = (lane & 16) != 0;
    float r[2];
#pragma unroll
    for (int j = 0; j < 2; j++) {
      float send = h4 ? q[j] : q[2 + j];
      float got = __shfl_xor(send, 16);
      r[j] = (h4 ? q[2 + j] : q[j]) + got;
    }
    bool h3 = (lane & 8) != 0;
    float send = h3 ? r[0] : r[1];
    float got = __shfl_xor(send, 8);
    float v = (h3 ? r[1] : r[0]) + got;
    v += __shfl_xor(v, 1);
    v += __shfl_xor(v, 2);
    v += __shfl_xor(v, 4);
    if ((lane & 7) == 0) {
      int s = lane >> 3;
      if (s < 4) s_src[node * HEADS + s] = v;
      else       s_dst[node * HEADS + (s - 4)] = v;
    }
  }

  // per-node histogram: 1.6M global atomics over 100K counters (~16/counter)
  int b = blockIdx.x;
  if (b < HB) {
    int t = threadIdx.x;
    int base = b * 8192;
#pragma unroll 4
    for (int j = 0; j < 32; j++) {
      int i = base + j * 256 + t;
      if (i < E) atomicAdd(&hist[src[i]], 1);
    }
  }
}

// ---------------- scan, pass 1: per-tile local scan (49 parallel blocks) -----
__global__ __launch_bounds__(256) void scan_local_kernel(
    const int* __restrict__ hist, int* __restrict__ fine_ptr,
    int* __restrict__ bsum, int n) {
  __shared__ int lds[256];
  int t = threadIdx.x;
  int base = blockIdx.x << 11;
  int loc[8];
  int s = 0;
#pragma unroll
  for (int j = 0; j < 8; j++) {
    int idx = base + t * 8 + j;
    loc[j] = (idx < n) ? hist[idx] : 0;
    s += loc[j];
  }
  lds[t] = s;
  __syncthreads();
  for (int off = 1; off < 256; off <<= 1) {
    int xv = (t >= off) ? lds[t - off] : 0;
    __syncthreads();
    lds[t] += xv;
    __syncthreads();
  }
  int run = lds[t] - s;   // tile-local exclusive prefix
#pragma unroll
  for (int j = 0; j < 8; j++) {
    int idx = base + t * 8 + j;
    if (idx < n) fine_ptr[idx] = run;
    run += loc[j];
  }
  if (t == 255) bsum[blockIdx.x] = lds[255];
}

// ---------------- scan, pass 2: add tile carries (49 parallel blocks) --------
__global__ __launch_bounds__(256) void scan_final_kernel(
    int* __restrict__ fine_ptr, int* __restrict__ cursor,
    const int* __restrict__ bsum, int n, int E, int NT) {
  __shared__ int carry_s;
  int t = threadIdx.x, b = blockIdx.x;
  if (t < 64) {
    int v = (t < b && t < NT) ? bsum[t] : 0;
#pragma unroll
    for (int off = 32; off > 0; off >>= 1) v += __shfl_xor(v, off);
    if (t == 0) carry_s = v;
  }
  __syncthreads();
  int carry = carry_s;
  int base = b << 11;
#pragma unroll
  for (int j = 0; j < 8; j++) {
    int idx = base + t * 8 + j;
    if (idx < n) {
      int v = fine_ptr[idx] + carry;
      fine_ptr[idx] = v;
      cursor[idx] = v;
    }
  }
  if (b == 0 && t == 0) fine_ptr[n] = E;
}

// ---------------- scatter: per-node counting-sort placement ------------------
// R8 bug: grid was E/8192 = 196 blocks -> 0.77 blocks/CU, 7% occupancy, 100us
// at 0.4% VALU (pure latency serialization of 32 dependent atomic->store
// chains per thread).  Now 1024 edges/block -> ~6 blocks/CU, ~24 waves/CU,
// 4 chains/thread in flight: ~8x the memory-level parallelism.
__global__ __launch_bounds__(256) void scatter_kernel(
    const int* __restrict__ src, const int* __restrict__ dst,
    const float* __restrict__ adj, int* __restrict__ cursor,
    int2* __restrict__ ebuf, int E) {
  int t = threadIdx.x;
  int base = blockIdx.x << 10;
#pragma unroll
  for (int j = 0; j < 4; j++) {
    int i = base + j * 256 + t;
    if (i < E) {
      int s = src[i];
      int slot = atomicAdd(&cursor[s], 1);
      int2 pk;
      pk.x = dst[i];
      pk.y = __float_as_int(adj[i]);
      ebuf[slot] = pk;
    }
  }
}

// ---------------- aggregate: CSR-direct, no preamble -------------------------
// One block per 16 nodes, 4 waves x 4 nodes; lane = (edge slot e=lane>>2,
// head k=lane&3).  Edges for a node are CONTIGUOUS in ebuf, so each chunk
// reads 16x8B = 128B coalesced, prefetched one chunk ahead (pkN: +2 VGPRs).
// Row gathers + score gather issue up front, ev phase + fma drain cover them.
// LDS = 1KB evbuf only -> launch_bounds(256,8), VGPR ~36: true 8 blocks/CU.
// Padding (e >= cn): pk={0,0} -> adj=0 -> ev=0, row 0 gather cached+discarded.
__global__ __launch_bounds__(256, 8) void aggregate_kernel(
    const unsigned int* __restrict__ xb, const float* __restrict__ W,
    const float* __restrict__ s_src, const float* __restrict__ s_dst,
    const int* __restrict__ fine_ptr, const int2* __restrict__ ebuf,
    float* __restrict__ out, int n) {
  __shared__ float evbuf[4][64];

  int t = threadIdx.x, b = blockIdx.x;
  int lane = t & 63, wid = t >> 6;
  int e = lane >> 2;                   // edge slot 0..15
  int k = lane & 3;                    // head

  for (int ni = 0; ni < 4; ni++) {
    int node = (b << 4) + wid * 4 + ni;
    if (node >= n) break;              // wave-uniform
    int eb = fine_ptr[node];
    int cnt = fine_ptr[node + 1] - eb;
    float ssrc_k = s_src[node * HEADS + k];

    v2f acc0{0.f,0.f}, acc1{0.f,0.f}, acc2{0.f,0.f}, acc3{0.f,0.f};
    float rsum = 0.f;

    int2 pkC{0, 0};
    if (e < cnt) pkC = ebuf[eb + e];

    int c = 0;
    while (c < cnt) {
      // ---- prefetch next chunk's edge record (in flight across this chunk)
      int2 pkN{0, 0};
      int cn2 = cnt - c - 16;
      if (cn2 > 0 && e < cn2) pkN = ebuf[eb + c + 16 + e];

      // ---- issue ALL long-latency gathers for current chunk up front ----
      float sdv = s_dst[pkC.x * HEADS + k];       // score gather (in flight)
      int dd[16];
#pragma unroll
      for (int j = 0; j < 16; j++)
        dd[j] = __builtin_amdgcn_readlane(pkC.x, j * 4);
      unsigned int xw[16];
#pragma unroll
      for (int j = 0; j < 16; j++)
        xw[j] = xb[(((size_t)(unsigned)dd[j]) << 6) + lane];  // 16 rows flying

      // ---- ev phase (waits only on sdv; rows still flying) ----
      float s = ssrc_k + sdv;
      s = (s >= 0.f) ? s : ALPHA * s;
      float ev = __expf(s) * __int_as_float(pkC.y);  // padded: adj=0 -> 0
      rsum += ev;
      evbuf[wid][lane] = ev;             // wave-private; in-order DS pipe

      // ---- fma drain ----
#pragma unroll
      for (int j = 0; j < 16; j++) {
        const float4 s4 = *(const float4*)&evbuf[wid][j * 4];
        v2f xv;
        xv.x = __uint_as_float(xw[j] << 16);
        xv.y = __uint_as_float(xw[j] & 0xffff0000u);
        acc0 += s4.x * xv;
        acc1 += s4.y * xv;
        acc2 += s4.z * xv;
        acc3 += s4.w * xv;
      }
      pkC = pkN;
      c += 16;
    }

    // rowsum per head (lane holds head lane&3 after the xor reduce)
    rsum += __shfl_xor(rsum, 4);
    rsum += __shfl_xor(rsum, 8);
    rsum += __shfl_xor(rsum, 16);
    rsum += __shfl_xor(rsum, 32);
    float rinv = __builtin_amdgcn_rcpf(rsum);   // 1 v_rcp vs 8 IEEE divides
    float r0 = readlane_f(rinv, 0), r1 = readlane_f(rinv, 1);
    float r2 = readlane_f(rinv, 2), r3 = readlane_f(rinv, 3);

    const float2* W2 = (const float2*)W;
    float2 o{0.f, 0.f};
    float hx, hy;
    {
      float2 wv = W2[0 * 64 + lane];
      hx = wv.x * acc0.x * r0; hy = wv.y * acc0.y * r0;
      o.x += (hx > 0.f) ? hx : (__expf(hx) - 1.f);
      o.y += (hy > 0.f) ? hy : (__expf(hy) - 1.f);
    }
    {
      float2 wv = W2[1 * 64 + lane];
      hx = wv.x * acc1.x * r1; hy = wv.y * acc1.y * r1;
      o.x += (hx > 0.f) ? hx : (__expf(hx) - 1.f);
      o.y += (hy > 0.f) ? hy : (__expf(hy) - 1.f);
    }
    {
      float2 wv = W2[2 * 64 + lane];
      hx = wv.x * acc2.x * r2; hy = wv.y * acc2.y * r2;
      o.x += (hx > 0.f) ? hx : (__expf(hx) - 1.f);
      o.y += (hy > 0.f) ? hy : (__expf(hy) - 1.f);
    }
    {
      float2 wv = W2[3 * 64 + lane];
      hx = wv.x * acc3.x * r3; hy = wv.y * acc3.y * r3;
      o.x += (hx > 0.f) ? hx : (__expf(hx) - 1.f);
      o.y += (hy > 0.f) ? hy : (__expf(hy) - 1.f);
    }
    o.x *= 0.25f; o.y *= 0.25f;
    ((float2*)out)[(size_t)node * 64 + lane] = o;
  }
}

extern "C" void kernel_launch(void* const* d_in, const int* in_sizes, int n_in,
                              void* d_out, int out_size, void* d_ws, size_t ws_size,
                              hipStream_t stream) {
  const float* x   = (const float*)d_in[0];
  const int*   edg = (const int*)d_in[1];
  const float* adj = (const float*)d_in[2];
  const float* W   = (const float*)d_in[3];
  const float* a   = (const float*)d_in[4];
  float* out = (float*)d_out;

  int E = in_sizes[2];
  int n = in_sizes[0] / FDIM;
  const int* src = edg;
  const int* dst = edg + E;
  int HB = (E + 8191) / 8192;          // histogram tiles (score edge slice)
  int SB = (E + 1023) / 1024;          // scatter blocks (~6/CU)
  int NT = (n + 2047) >> 11;           // scan tiles (<= 64 for n <= 131072)

  auto align = [](size_t v) { return (v + 255) & ~(size_t)255; };
  char* ws = (char*)d_ws;
  int*   fine_ptr = (int*)ws;          ws += align((size_t)(n + 1) * 4);
  int*   cursor   = (int*)ws;          ws += align((size_t)n * 4);
  int*   hist     = (int*)ws;          ws += align((size_t)n * 4);
  int*   bsum     = (int*)ws;          ws += align((size_t)NT * 4);
  int2*  ebuf     = (int2*)ws;         ws += align((size_t)E * 8);
  float* s_src    = (float*)ws;        ws += align((size_t)n * HEADS * 4);
  float* s_dst    = (float*)ws;        ws += align((size_t)n * HEADS * 4);
  unsigned int* xb = (unsigned int*)ws; ws += align((size_t)n * 64 * 4);

  hipMemsetAsync(hist, 0, (size_t)n * 4, stream);

  score_kernel<<<(n + 3) / 4, 256, 0, stream>>>(x, W, a, s_src, s_dst, xb,
                                                src, hist, E, HB, n);
  scan_local_kernel<<<NT, 256, 0, stream>>>(hist, fine_ptr, bsum, n);
  scan_final_kernel<<<NT, 256, 0, stream>>>(fine_ptr, cursor, bsum, n, E, NT);
  scatter_kernel<<<SB, 256, 0, stream>>>(src, dst, adj, cursor, ebuf, E);
  aggregate_kernel<<<(n + 15) / 16, 256, 0, stream>>>(xb, W, s_src, s_dst,
                                                      fine_ptr, ebuf, out, n);
}

// Round 10
// 351.701 us; speedup vs baseline: 1.0885x; 1.0885x over previous
//
#include <hip/hip_runtime.h>

#define FDIM   128
#define HEADS  4
#define ALPHA  0.2f

typedef float v2f __attribute__((ext_vector_type(2)));

__device__ __forceinline__ float readlane_f(float v, int lane) {
  return __int_as_float(__builtin_amdgcn_readlane(__float_as_int(v), lane));
}

// ------- per-node scores + bf16-pack of x + per-NODE edge histogram ----------
__global__ __launch_bounds__(256) void score_kernel(
    const float* __restrict__ x, const float* __restrict__ W,
    const float* __restrict__ a, float* __restrict__ s_src,
    float* __restrict__ s_dst, unsigned int* __restrict__ xb,
    const int* __restrict__ src, int* __restrict__ hist,
    int E, int HB, int n) {
  int lane = threadIdx.x & 63;
  int node = (blockIdx.x << 2) + (threadIdx.x >> 6);
  if (node < n) {
    const float2* x2 = (const float2*)x;
    const float2* W2 = (const float2*)W;
    const float2* a2 = (const float2*)a;
    float2 xv = x2[(size_t)node * 64 + lane];

    // bf16 pack (round-to-nearest-even)
    unsigned int u0 = __float_as_uint(xv.x);
    unsigned int u1 = __float_as_uint(xv.y);
    u0 += 0x7fffu + ((u0 >> 16) & 1u);
    u1 += 0x7fffu + ((u1 >> 16) & 1u);
    xb[(size_t)node * 64 + lane] = (u0 >> 16) | (u1 & 0xffff0000u);

    float p[8];   // p[0..3] = rs per head, p[4..7] = rd per head
#pragma unroll
    for (int k = 0; k < HEADS; k++) {
      float2 wv = W2[k * 64 + lane];
      float hx = xv.x * wv.x, hy = xv.y * wv.y;
      float2 as_ = a2[k * 128 + lane];        // a[k, 0:F]
      float2 ad_ = a2[k * 128 + 64 + lane];   // a[k, F:2F]
      p[k]     = hx * as_.x + hy * as_.y;
      p[4 + k] = hx * ad_.x + hy * ad_.y;
    }

    bool h5 = (lane & 32) != 0;
    float q[4];
#pragma unroll
    for (int k = 0; k < 4; k++) {
      float send = h5 ? p[k] : p[4 + k];
      float got = __shfl_xor(send, 32);
      q[k] = (h5 ? p[4 + k] : p[k]) + got;
    }
    bool h4 = (lane & 16) != 0;
    float r[2];
#pragma unroll
    for (int j = 0; j < 2; j++) {
      float send = h4 ? q[j] : q[2 + j];
      float got = __shfl_xor(send, 16);
      r[j] = (h4 ? q[2 + j] : q[j]) + got;
    }
    bool h3 = (lane & 8) != 0;
    float send = h3 ? r[0] : r[1];
    float got = __shfl_xor(send, 8);
    float v = (h3 ? r[1] : r[0]) + got;
    v += __shfl_xor(v, 1);
    v += __shfl_xor(v, 2);
    v += __shfl_xor(v, 4);
    if ((lane & 7) == 0) {
      int s = lane >> 3;
      if (s < 4) s_src[node * HEADS + s] = v;
      else       s_dst[node * HEADS + (s - 4)] = v;
    }
  }

  // per-node histogram: 1.6M global atomics over 100K counters (~16/counter)
  int b = blockIdx.x;
  if (b < HB) {
    int t = threadIdx.x;
    int base = b * 8192;
#pragma unroll 4
    for (int j = 0; j < 32; j++) {
      int i = base + j * 256 + t;
      if (i < E) atomicAdd(&hist[src[i]], 1);
    }
  }
}

// ---------------- scan, pass 1: per-tile local scan ------------------------
__global__ __launch_bounds__(256) void scan_local_kernel(
    const int* __restrict__ hist, int* __restrict__ fine_ptr,
    int* __restrict__ bsum, int n) {
  __shared__ int lds[256];
  int t = threadIdx.x;
  int base = blockIdx.x << 11;
  int loc[8];
  int s = 0;
#pragma unroll
  for (int j = 0; j < 8; j++) {
    int idx = base + t * 8 + j;
    loc[j] = (idx < n) ? hist[idx] : 0;
    s += loc[j];
  }
  lds[t] = s;
  __syncthreads();
  for (int off = 1; off < 256; off <<= 1) {
    int xv = (t >= off) ? lds[t - off] : 0;
    __syncthreads();
    lds[t] += xv;
    __syncthreads();
  }
  int run = lds[t] - s;   // tile-local exclusive prefix
#pragma unroll
  for (int j = 0; j < 8; j++) {
    int idx = base + t * 8 + j;
    if (idx < n) fine_ptr[idx] = run;
    run += loc[j];
  }
  if (t == 255) bsum[blockIdx.x] = lds[255];
}

// ---------------- scan, pass 2: add carries; emit fine + coarse bases --------
// Also writes cbase[c]/ccur[c] (coarse bucket = 1024 nodes) for the two-pass
// scatter: cbase = read-only bucket base, ccur = pass-A reservation cursor.
__global__ __launch_bounds__(256) void scan_final_kernel(
    int* __restrict__ fine_ptr, int* __restrict__ cursor,
    const int* __restrict__ bsum, int* __restrict__ cbase,
    int* __restrict__ ccur, int n, int E, int NT, int NC) {
  __shared__ int carry_s;
  int t = threadIdx.x, b = blockIdx.x;
  if (t < 64) {
    int v = (t < b && t < NT) ? bsum[t] : 0;
#pragma unroll
    for (int off = 32; off > 0; off >>= 1) v += __shfl_xor(v, off);
    if (t == 0) carry_s = v;
  }
  __syncthreads();
  int carry = carry_s;
  int base = b << 11;
#pragma unroll
  for (int j = 0; j < 8; j++) {
    int idx = base + t * 8 + j;
    if (idx < n) {
      int v = fine_ptr[idx] + carry;
      fine_ptr[idx] = v;
      cursor[idx] = v;
      if ((idx & 1023) == 0) {
        cbase[idx >> 10] = v;
        ccur[idx >> 10]  = v;
      }
    }
  }
  if (b == 0 && t == 0) { fine_ptr[n] = E; cbase[NC] = E; }
}

// ---------------- scatter pass A: coarse counting-sort (coalesced writes) ----
// 98 coarse buckets of 1024 nodes.  Per 2048-edge block: LDS hist -> ONE
// global atomicAdd per nonzero bucket reserves a contiguous chunk -> records
// stream into the chunk (~21 edges = 168B contiguous per (block,bucket)).
// This replaces R9's random-8B scatter whose 64B-line amplification (97.8MB
// writes for 12.8MB payload, ~860GB/s effective) was the 127us bottleneck.
// Record packs src_local (10b) + dst (20b) into pk.x -- no extra array.
__global__ __launch_bounds__(256) void coarse_kernel(
    const int* __restrict__ src, const int* __restrict__ dst,
    const float* __restrict__ adj, int* __restrict__ ccur,
    int2* __restrict__ ebufA, int E) {
  __shared__ int h[128];
  __shared__ int base_s[128];
  __shared__ int rank_s[128];
  int t = threadIdx.x;
  int base = blockIdx.x << 11;
  if (t < 128) h[t] = 0;
  __syncthreads();
  int s0[8];
#pragma unroll
  for (int j = 0; j < 8; j++) {
    int i = base + j * 256 + t;
    s0[j] = (i < E) ? src[i] : -1;
    if (s0[j] >= 0) atomicAdd(&h[s0[j] >> 10], 1);
  }
  __syncthreads();
  if (t < 128) {
    rank_s[t] = 0;
    int c = h[t];
    base_s[t] = (c > 0) ? atomicAdd(&ccur[t], c) : 0;
  }
  __syncthreads();
#pragma unroll
  for (int j = 0; j < 8; j++) {
    int i = base + j * 256 + t;
    if (s0[j] >= 0) {
      int bk = s0[j] >> 10;
      int r = atomicAdd(&rank_s[bk], 1);
      int2 pk;
      pk.x = (int)(((unsigned)(s0[j] & 1023) << 20) | (unsigned)dst[i]);
      pk.y = __float_as_int(adj[i]);
      ebufA[base_s[bk] + r] = pk;
    }
  }
}

// ---------------- scatter pass B: fine placement, L2-local windows -----------
// Edges are grouped by coarse bucket, so this block's random writes span only
// its bucket's ~131KB ebuf window + 4KB cursor window -> L2-resident, each
// line filled then written back once.  Bijective XCD swizzle (contiguous
// block ranges per XCD) keeps blocks sharing a bucket on ONE L2.
// Bucket id recovered by binary search over cbase in LDS (<=7 steps).
__global__ __launch_bounds__(256) void fine_kernel(
    const int2* __restrict__ ebufA, const int* __restrict__ cbase,
    int* __restrict__ cursor, int2* __restrict__ ebuf, int E, int NC) {
  __shared__ int cb[129];
  int t = threadIdx.x;
  int nb = gridDim.x;
  int xcd = blockIdx.x & 7, idx = blockIdx.x >> 3;
  int q = nb >> 3, r = nb & 7;
  int w = (xcd < r ? xcd * (q + 1) : r * (q + 1) + (xcd - r) * q) + idx;
  int e0 = w << 11;
  for (int i = t; i <= NC; i += 256) cb[i] = cbase[i];
  __syncthreads();
#pragma unroll
  for (int j = 0; j < 8; j++) {
    int i = e0 + j * 256 + t;
    if (i < E) {
      int2 pk = ebufA[i];
      int lo = 0, hi = NC - 1;
      while (lo < hi) {                 // largest c with cb[c] <= i
        int mid = (lo + hi + 1) >> 1;
        if (cb[mid] <= i) lo = mid; else hi = mid - 1;
      }
      int srcn = (lo << 10) + (int)((unsigned)pk.x >> 20);
      int slot = atomicAdd(&cursor[srcn], 1);
      int2 o;
      o.x = pk.x & 0xFFFFF;
      o.y = pk.y;
      ebuf[slot] = o;
    }
  }
}

// ---------------- aggregate: CSR-direct, no preamble -------------------------
// One block per 16 nodes, 4 waves x 4 nodes; lane = (edge slot e=lane>>2,
// head k=lane&3).  Edges for a node are CONTIGUOUS in ebuf, so each chunk
// reads 16x8B = 128B coalesced, prefetched one chunk ahead (pkN: +2 VGPRs).
// Row gathers + score gather issue up front, ev phase + fma drain cover them.
// Padding (e >= cn): pk={0,0} -> adj=0 -> ev=0, row 0 gather cached+discarded.
__global__ __launch_bounds__(256, 8) void aggregate_kernel(
    const unsigned int* __restrict__ xb, const float* __restrict__ W,
    const float* __restrict__ s_src, const float* __restrict__ s_dst,
    const int* __restrict__ fine_ptr, const int2* __restrict__ ebuf,
    float* __restrict__ out, int n) {
  __shared__ float evbuf[4][64];

  int t = threadIdx.x, b = blockIdx.x;
  int lane = t & 63, wid = t >> 6;
  int e = lane >> 2;                   // edge slot 0..15
  int k = lane & 3;                    // head

  for (int ni = 0; ni < 4; ni++) {
    int node = (b << 4) + wid * 4 + ni;
    if (node >= n) break;              // wave-uniform
    int eb = fine_ptr[node];
    int cnt = fine_ptr[node + 1] - eb;
    float ssrc_k = s_src[node * HEADS + k];

    v2f acc0{0.f,0.f}, acc1{0.f,0.f}, acc2{0.f,0.f}, acc3{0.f,0.f};
    float rsum = 0.f;

    int2 pkC{0, 0};
    if (e < cnt) pkC = ebuf[eb + e];

    int c = 0;
    while (c < cnt) {
      // ---- prefetch next chunk's edge record (in flight across this chunk)
      int2 pkN{0, 0};
      int cn2 = cnt - c - 16;
      if (cn2 > 0 && e < cn2) pkN = ebuf[eb + c + 16 + e];

      // ---- issue ALL long-latency gathers for current chunk up front ----
      float sdv = s_dst[pkC.x * HEADS + k];       // score gather (in flight)
      int dd[16];
#pragma unroll
      for (int j = 0; j < 16; j++)
        dd[j] = __builtin_amdgcn_readlane(pkC.x, j * 4);
      unsigned int xw[16];
#pragma unroll
      for (int j = 0; j < 16; j++)
        xw[j] = xb[(((size_t)(unsigned)dd[j]) << 6) + lane];  // 16 rows flying

      // ---- ev phase (waits only on sdv; rows still flying) ----
      float s = ssrc_k + sdv;
      s = (s >= 0.f) ? s : ALPHA * s;
      float ev = __expf(s) * __int_as_float(pkC.y);  // padded: adj=0 -> 0
      rsum += ev;
      evbuf[wid][lane] = ev;             // wave-private; in-order DS pipe

      // ---- fma drain ----
#pragma unroll
      for (int j = 0; j < 16; j++) {
        const float4 s4 = *(const float4*)&evbuf[wid][j * 4];
        v2f xv;
        xv.x = __uint_as_float(xw[j] << 16);
        xv.y = __uint_as_float(xw[j] & 0xffff0000u);
        acc0 += s4.x * xv;
        acc1 += s4.y * xv;
        acc2 += s4.z * xv;
        acc3 += s4.w * xv;
      }
      pkC = pkN;
      c += 16;
    }

    // rowsum per head (lane holds head lane&3 after the xor reduce)
    rsum += __shfl_xor(rsum, 4);
    rsum += __shfl_xor(rsum, 8);
    rsum += __shfl_xor(rsum, 16);
    rsum += __shfl_xor(rsum, 32);
    float rinv = __builtin_amdgcn_rcpf(rsum);   // 1 v_rcp vs 8 IEEE divides
    float r0 = readlane_f(rinv, 0), r1 = readlane_f(rinv, 1);
    float r2 = readlane_f(rinv, 2), r3 = readlane_f(rinv, 3);

    const float2* W2 = (const float2*)W;
    float2 o{0.f, 0.f};
    float hx, hy;
    {
      float2 wv = W2[0 * 64 + lane];
      hx = wv.x * acc0.x * r0; hy = wv.y * acc0.y * r0;
      o.x += (hx > 0.f) ? hx : (__expf(hx) - 1.f);
      o.y += (hy > 0.f) ? hy : (__expf(hy) - 1.f);
    }
    {
      float2 wv = W2[1 * 64 + lane];
      hx = wv.x * acc1.x * r1; hy = wv.y * acc1.y * r1;
      o.x += (hx > 0.f) ? hx : (__expf(hx) - 1.f);
      o.y += (hy > 0.f) ? hy : (__expf(hy) - 1.f);
    }
    {
      float2 wv = W2[2 * 64 + lane];
      hx = wv.x * acc2.x * r2; hy = wv.y * acc2.y * r2;
      o.x += (hx > 0.f) ? hx : (__expf(hx) - 1.f);
      o.y += (hy > 0.f) ? hy : (__expf(hy) - 1.f);
    }
    {
      float2 wv = W2[3 * 64 + lane];
      hx = wv.x * acc3.x * r3; hy = wv.y * acc3.y * r3;
      o.x += (hx > 0.f) ? hx : (__expf(hx) - 1.f);
      o.y += (hy > 0.f) ? hy : (__expf(hy) - 1.f);
    }
    o.x *= 0.25f; o.y *= 0.25f;
    ((float2*)out)[(size_t)node * 64 + lane] = o;
  }
}

extern "C" void kernel_launch(void* const* d_in, const int* in_sizes, int n_in,
                              void* d_out, int out_size, void* d_ws, size_t ws_size,
                              hipStream_t stream) {
  const float* x   = (const float*)d_in[0];
  const int*   edg = (const int*)d_in[1];
  const float* adj = (const float*)d_in[2];
  const float* W   = (const float*)d_in[3];
  const float* a   = (const float*)d_in[4];
  float* out = (float*)d_out;

  int E = in_sizes[2];
  int n = in_sizes[0] / FDIM;
  const int* src = edg;
  const int* dst = edg + E;
  int HB = (E + 8191) / 8192;          // histogram tiles (score edge slice)
  int SB = (E + 2047) / 2048;          // scatter pass blocks (2048 edges each)
  int NT = (n + 2047) >> 11;           // scan tiles (<= 64 for n <= 131072)
  int NC = (n + 1023) >> 10;           // coarse buckets (<= 128)

  auto align = [](size_t v) { return (v + 255) & ~(size_t)255; };
  char* ws = (char*)d_ws;
  int*   fine_ptr = (int*)ws;          ws += align((size_t)(n + 1) * 4);
  int*   cursor   = (int*)ws;          ws += align((size_t)n * 4);
  int*   hist     = (int*)ws;          ws += align((size_t)n * 4);
  int*   bsum     = (int*)ws;          ws += align((size_t)NT * 4);
  int*   cbase    = (int*)ws;          ws += align((size_t)132 * 4);
  int*   ccur     = (int*)ws;          ws += align((size_t)132 * 4);
  int2*  ebufA    = (int2*)ws;         ws += align((size_t)E * 8);
  int2*  ebuf     = (int2*)ws;         ws += align((size_t)E * 8);
  float* s_src    = (float*)ws;        ws += align((size_t)n * HEADS * 4);
  float* s_dst    = (float*)ws;        ws += align((size_t)n * HEADS * 4);
  unsigned int* xb = (unsigned int*)ws; ws += align((size_t)n * 64 * 4);

  hipMemsetAsync(hist, 0, (size_t)n * 4, stream);

  score_kernel<<<(n + 3) / 4, 256, 0, stream>>>(x, W, a, s_src, s_dst, xb,
                                                src, hist, E, HB, n);
  scan_local_kernel<<<NT, 256, 0, stream>>>(hist, fine_ptr, bsum, n);
  scan_final_kernel<<<NT, 256, 0, stream>>>(fine_ptr, cursor, bsum, cbase,
                                            ccur, n, E, NT, NC);
  coarse_kernel<<<SB, 256, 0, stream>>>(src, dst, adj, ccur, ebufA, E);
  fine_kernel<<<SB, 256, 0, stream>>>(ebufA, cbase, cursor, ebuf, E, NC);
  aggregate_kernel<<<(n + 15) / 16, 256, 0, stream>>>(xb, W, s_src, s_dst,
                                                      fine_ptr, ebuf, out, n);
}